// Round 3
// baseline (635.706 us; speedup 1.0000x reference)
//
#include <hip/hip_runtime.h>
#include <math.h>

#define N_NODES 25000
#define E_EDGES 250000
#define HID 128
#define OUTC 64
#define NPB 98          // ceil(25000/256)

using bf16x8 = __attribute__((ext_vector_type(8))) short;
using f32x4  = __attribute__((ext_vector_type(4))) float;

__device__ __forceinline__ unsigned short f2bf(float f) {   // RNE float->bf16
    unsigned u = __float_as_uint(f);
    u = (u + 0x7fffu + ((u >> 16) & 1u)) >> 16;
    return (unsigned short)u;
}
__device__ __forceinline__ float bf2f(unsigned short h) {
    return __uint_as_float(((unsigned)h) << 16);
}
__device__ __forceinline__ float gelu_f(float x) {
    return 0.5f * x * (1.0f + erff(x * 0.70710678118654752440f));
}

// ============================ CSR build ============================
__global__ void hist2(const int* __restrict__ e0, const int* __restrict__ e1,
                      int* __restrict__ cnt) {
    int r = blockIdx.y;
    const int* d = (r ? e1 : e0) + E_EDGES;
    int e = blockIdx.x * 256 + threadIdx.x;
    if (e < E_EDGES) atomicAdd(&cnt[r * N_NODES + d[e]], 1);
}

__global__ void csr_partial(const int* __restrict__ cnt, int* __restrict__ part) {
    int r = blockIdx.y, b = blockIdx.x, t = threadIdx.x;
    int idx = b * 256 + t;
    int v = (idx < N_NODES) ? cnt[r * N_NODES + idx] : 0;
    #pragma unroll
    for (int d = 1; d < 64; d <<= 1) v += __shfl_xor(v, d);
    __shared__ int ws[4];
    if ((t & 63) == 0) ws[t >> 6] = v;
    __syncthreads();
    if (t == 0) part[r * NPB + b] = ws[0] + ws[1] + ws[2] + ws[3];
}

__global__ void csr_scanpart(int* __restrict__ part) {
    int w = threadIdx.x >> 6, lane = threadIdx.x & 63;
    int base = w * NPB;
    int a = part[base + lane];
    int b = (lane < NPB - 64) ? part[base + 64 + lane] : 0;
    int va = a, vb = b;
    #pragma unroll
    for (int d = 1; d < 64; d <<= 1) { int u = __shfl_up(va, d); if (lane >= d) va += u; }
    #pragma unroll
    for (int d = 1; d < 64; d <<= 1) { int u = __shfl_up(vb, d); if (lane >= d) vb += u; }
    int tot0 = __shfl(va, 63);
    part[base + lane] = va - a;
    if (lane < NPB - 64) part[base + 64 + lane] = vb - b + tot0;
}

__global__ void csr_write(int* __restrict__ cnt, const int* __restrict__ part,
                          int* __restrict__ rowptr) {
    int r = blockIdx.y, b = blockIdx.x, t = threadIdx.x;
    int idx = b * 256 + t;
    int v = (idx < N_NODES) ? cnt[r * N_NODES + idx] : 0;
    int lane = t & 63, w = t >> 6;
    int iv = v;
    #pragma unroll
    for (int d = 1; d < 64; d <<= 1) { int u = __shfl_up(iv, d); if (lane >= d) iv += u; }
    __shared__ int wtot[4];
    if (lane == 63) wtot[w] = iv;
    __syncthreads();
    int woff = part[r * NPB + b];
    #pragma unroll
    for (int i = 0; i < 4; i++) if (i < w) woff += wtot[i];
    int excl = woff + iv - v;
    if (idx < N_NODES) {
        rowptr[r * (N_NODES + 1) + idx] = excl;
        cnt[r * N_NODES + idx] = excl;
    }
    if (b == 0 && t == 0) rowptr[r * (N_NODES + 1) + N_NODES] = E_EDGES;
}

__global__ void scatter2(const int* __restrict__ e0, const int* __restrict__ e1,
                         int* __restrict__ cursor, int* __restrict__ srcs) {
    int r = blockIdx.y;
    const int* e = r ? e1 : e0;
    int i = blockIdx.x * 256 + threadIdx.x;
    if (i < E_EDGES) {
        int p = atomicAdd(&cursor[r * N_NODES + e[E_EDGES + i]], 1);
        srcs[r * E_EDGES + p] = e[i];
    }
}

// =============== weight prep: transpose fp32 [128][C] -> bf16 [C][128] ===============
__global__ void tconv(const float* __restrict__ src, unsigned short* __restrict__ dst, int C) {
    int m = blockIdx.y;
    int idx = blockIdx.x * 256 + threadIdx.x;
    if (idx >= C * 128) return;
    int c = idx >> 7, k = idx & 127;
    dst[(size_t)m * C * 128 + idx] = f2bf(src[(size_t)m * 128 * C + k * C + c]);
}

// fused QKV' weights, transposed bf16 [p][384col][128k] + fp32 bias [p][384]
__global__ __launch_bounds__(256) void prep_qkv(
    const float* __restrict__ Wq, const float* __restrict__ bq,
    const float* __restrict__ Wk, const float* __restrict__ bk,
    const float* __restrict__ Wv, const float* __restrict__ bv,
    const float* __restrict__ a_rel, const float* __restrict__ m_rel,
    unsigned short* __restrict__ WT, float* __restrict__ bfq)
{
    int p = blockIdx.x;                    // l*2+t (relation r == source type t)
    __shared__ float sA[2048], sM[2048];
    for (int i = threadIdx.x; i < 2048; i += 256) {
        sA[i] = a_rel[p * 2048 + i];
        sM[i] = m_rel[p * 2048 + i];
    }
    __syncthreads();
    const float* wq = Wq + (size_t)p * 16384;
    const float* wk = Wk + (size_t)p * 16384;
    const float* wv = Wv + (size_t)p * 16384;
    unsigned short* wt = WT + (size_t)p * 384 * 128;
    float* bp = bfq + p * 384;
    for (int idx = threadIdx.x; idx < 384 * 129; idx += 256) {
        int c = idx % 384;
        int ik = idx / 384;                // 0..127 weight row, 128 = bias
        float val;
        if (c < 128) {
            val = (ik < 128) ? wq[ik * 128 + c] : bq[p * 128 + c];
        } else if (c < 256) {
            int cc = c - 128, h = cc >> 4, f = cc & 15;
            const float* row = (ik < 128) ? &wk[ik * 128 + h * 16] : &bk[p * 128 + h * 16];
            float s = 0.f;
            #pragma unroll
            for (int d = 0; d < 16; d++) s = fmaf(row[d], sA[h * 256 + d * 16 + f], s);
            val = s;
        } else {
            int cc = c - 256, h = cc >> 4, f = cc & 15;
            const float* row = (ik < 128) ? &wv[ik * 128 + h * 16] : &bv[p * 128 + h * 16];
            float s = 0.f;
            #pragma unroll
            for (int d = 0; d < 16; d++) s = fmaf(row[d], sM[h * 256 + d * 16 + f], s);
            val = s;
        }
        if (ik < 128) wt[(size_t)c * 128 + ik] = f2bf(val);
        else bp[c] = val;
    }
}

// ============================ MFMA matmul ============================
// C[z] = epilogue(A[z][nrows,128] @ WT[z]^T + b[z]).  WT is bf16 [NOUT][128].
// No LDS: each wave owns 16 rows; A and B fragments loaded directly (16B/lane).
// OUTMODE: 0 bf16 store, 1 relu+bf16, 2 gated residual bf16 (in-place), 3 fp32 store.
template<int NOUT, int GELU_IN, int OUTMODE, int A_FP32>
__global__ __launch_bounds__(256) void mm3_kernel(
    const void* __restrict__ A0, const void* __restrict__ A1,
    const unsigned short* __restrict__ W0, const unsigned short* __restrict__ W1,
    const float* __restrict__ b0, const float* __restrict__ b1,
    const unsigned short* __restrict__ res0, const unsigned short* __restrict__ res1,
    const float* __restrict__ skipp,
    void* __restrict__ C0, void* __restrict__ C1, int nrows)
{
    constexpr int NF = NOUT / 16;
    int z = blockIdx.z;
    const void* Av = z ? A1 : A0;
    const unsigned short* W = z ? W1 : W0;
    const float* bias = z ? b1 : b0;
    const unsigned short* res = z ? res1 : res0;
    void* Cv = z ? C1 : C0;

    int t = threadIdx.x;
    int w = t >> 6, lane = t & 63;
    int lo = lane & 15, hi = lane >> 4;
    int rbase = blockIdx.x * 64 + w * 16;
    int ra = rbase + lo; if (ra > nrows - 1) ra = nrows - 1;

    bf16x8 a[4];
    if (A_FP32) {
        const float* Arow = (const float*)Av + (size_t)ra * HID;
        #pragma unroll
        for (int kk = 0; kk < 4; kk++) {
            const float* p4 = Arow + kk * 32 + hi * 8;
            float4 x0 = *(const float4*)p4;
            float4 x1 = *(const float4*)(p4 + 4);
            bf16x8 v;
            v[0] = (short)f2bf(x0.x); v[1] = (short)f2bf(x0.y);
            v[2] = (short)f2bf(x0.z); v[3] = (short)f2bf(x0.w);
            v[4] = (short)f2bf(x1.x); v[5] = (short)f2bf(x1.y);
            v[6] = (short)f2bf(x1.z); v[7] = (short)f2bf(x1.w);
            a[kk] = v;
        }
    } else {
        const unsigned short* Arow = (const unsigned short*)Av + (size_t)ra * HID;
        #pragma unroll
        for (int kk = 0; kk < 4; kk++) {
            bf16x8 v = *(const bf16x8*)(Arow + kk * 32 + hi * 8);
            if (GELU_IN) {
                #pragma unroll
                for (int j = 0; j < 8; j++)
                    v[j] = (short)f2bf(gelu_f(bf2f((unsigned short)v[j])));
            }
            a[kk] = v;
        }
    }

    f32x4 acc[NF];
    #pragma unroll
    for (int c = 0; c < NF; c++) acc[c] = (f32x4){0.f, 0.f, 0.f, 0.f};

    #pragma unroll
    for (int c = 0; c < NF; c++) {
        const unsigned short* Brow = W + (size_t)(c * 16 + lo) * HID + hi * 8;
        bf16x8 bf0 = *(const bf16x8*)(Brow);
        bf16x8 bf1 = *(const bf16x8*)(Brow + 32);
        bf16x8 bf2 = *(const bf16x8*)(Brow + 64);
        bf16x8 bf3 = *(const bf16x8*)(Brow + 96);
        acc[c] = __builtin_amdgcn_mfma_f32_16x16x32_bf16(a[0], bf0, acc[c], 0, 0, 0);
        acc[c] = __builtin_amdgcn_mfma_f32_16x16x32_bf16(a[1], bf1, acc[c], 0, 0, 0);
        acc[c] = __builtin_amdgcn_mfma_f32_16x16x32_bf16(a[2], bf2, acc[c], 0, 0, 0);
        acc[c] = __builtin_amdgcn_mfma_f32_16x16x32_bf16(a[3], bf3, acc[c], 0, 0, 0);
    }

    float beta = 0.f, omb = 0.f;
    if (OUTMODE == 2) { float sv = skipp[z]; beta = 1.f / (1.f + __expf(-sv)); omb = 1.f - beta; }
    #pragma unroll
    for (int c = 0; c < NF; c++) {
        int col = c * 16 + lo;
        float bb = bias[col];
        #pragma unroll
        for (int j = 0; j < 4; j++) {
            int r = rbase + hi * 4 + j;
            if (r >= nrows) continue;
            float v = acc[c][j] + bb;
            if (OUTMODE == 1) v = fmaxf(v, 0.f);
            if (OUTMODE == 2) v = beta * v + omb * bf2f(res[(size_t)r * HID + col]);
            if (OUTMODE == 3) ((float*)Cv)[(size_t)r * NOUT + col] = v;
            else ((unsigned short*)Cv)[(size_t)r * NOUT + col] = f2bf(v);
        }
    }
}

// ==================== attention: 32 lanes per dst node, bf16 gather ====================
__global__ __launch_bounds__(256) void attn3_kernel(
    const unsigned short* __restrict__ qkv0, const unsigned short* __restrict__ qkv1,
    const int* __restrict__ rowptr, const int* __restrict__ srcs,
    const float* __restrict__ prel,
    unsigned short* __restrict__ agg0, unsigned short* __restrict__ agg1, int n)
{
    int r = blockIdx.y;                    // relation; src type = r, dst type = 1-r
    const unsigned short* qd = r ? qkv0 : qkv1;
    const unsigned short* sv = r ? qkv1 : qkv0;
    unsigned short* agg      = r ? agg0 : agg1;
    const int* rp = rowptr + r * (N_NODES + 1);
    const int* ss = srcs + r * E_EDGES;

    int gid = blockIdx.x * 256 + threadIdx.x;
    int nid = gid >> 5, lane = gid & 31;
    if (nid >= n) return;
    int c0 = lane << 2;
    int h = lane >> 2;
    const unsigned short* qrow = qd + (size_t)nid * 384 + c0;
    float q0 = bf2f(qrow[0]), q1 = bf2f(qrow[1]), q2 = bf2f(qrow[2]), q3 = bf2f(qrow[3]);
    float p = prel[r * 8 + h] * 0.25f;
    float m = -INFINITY, ssum = 0.f;
    float ax = 0.f, ay = 0.f, az = 0.f, aw = 0.f;
    int beg = rp[nid], end = rp[nid + 1];
    for (int i = beg; i < end; i++) {
        int s = ss[i];
        const unsigned short* srow = sv + (size_t)s * 384;
        ushort4 kv = *(const ushort4*)(srow + 128 + c0);
        ushort4 vv = *(const ushort4*)(srow + 256 + c0);
        float part = q0 * bf2f(kv.x) + q1 * bf2f(kv.y) + q2 * bf2f(kv.z) + q3 * bf2f(kv.w);
        part += __shfl_xor(part, 1);
        part += __shfl_xor(part, 2);
        float score = part * p;
        float nm = fmaxf(m, score);
        float resc = __expf(m - nm);
        float e = __expf(score - nm);
        ssum = ssum * resc + e;
        ax = ax * resc + e * bf2f(vv.x);
        ay = ay * resc + e * bf2f(vv.y);
        az = az * resc + e * bf2f(vv.z);
        aw = aw * resc + e * bf2f(vv.w);
        m = nm;
    }
    float inv = 1.f / (ssum + 1e-16f);
    ushort4 o;
    o.x = f2bf(ax * inv); o.y = f2bf(ay * inv);
    o.z = f2bf(az * inv); o.w = f2bf(aw * inv);
    *(ushort4*)(agg + (size_t)nid * HID + c0) = o;
}

// ============================ orchestration ============================
extern "C" void kernel_launch(void* const* d_in, const int* in_sizes, int n_in,
                              void* d_out, int out_size, void* d_ws, size_t ws_size,
                              hipStream_t stream)
{
    (void)in_sizes; (void)n_in; (void)out_size; (void)ws_size;
    const float* x_author = (const float*)d_in[0];
    const float* x_paper  = (const float*)d_in[1];
    const int*   e_writes = (const int*)d_in[2];
    const int*   e_rev    = (const int*)d_in[3];
    const float* W_in = (const float*)d_in[4];
    const float* b_in = (const float*)d_in[5];
    const float* Wq = (const float*)d_in[6];
    const float* bq = (const float*)d_in[7];
    const float* Wk = (const float*)d_in[8];
    const float* bk = (const float*)d_in[9];
    const float* Wv = (const float*)d_in[10];
    const float* bv = (const float*)d_in[11];
    const float* Wa = (const float*)d_in[12];
    const float* ba = (const float*)d_in[13];
    const float* skip = (const float*)d_in[14];
    const float* a_rel = (const float*)d_in[15];
    const float* m_rel = (const float*)d_in[16];
    const float* p_rel = (const float*)d_in[17];
    const float* W_out = (const float*)d_in[18];
    const float* b_out = (const float*)d_in[19];
    float* out = (float*)d_out;

    const size_t NC = (size_t)N_NODES * HID;       // 3.2M elems
    const size_t NQ = (size_t)N_NODES * 384;
    unsigned short* U = (unsigned short*)d_ws;
    unsigned short* cur0 = U;             unsigned short* cur1 = U + NC;
    unsigned short* agg0 = U + 2 * NC;    unsigned short* agg1 = U + 3 * NC;
    unsigned short* qkv0 = U + 4 * NC;    unsigned short* qkv1 = U + 4 * NC + NQ;
    unsigned short* WTin  = U + 4 * NC + 2 * NQ;            // 2*128*128
    unsigned short* WTqkv = WTin + 2 * 16384;               // 4*384*128
    unsigned short* WTa   = WTqkv + 4 * 49152;              // 4*128*128
    unsigned short* WTout = WTa + 4 * 16384;                // 64*128
    float* bfq = (float*)(WTout + OUTC * 128);              // 4*384 fp32
    int* I      = (int*)(bfq + 4 * 384);
    int* cnt    = I;
    int* part   = I + 2 * N_NODES;
    int* rowptr = part + 2 * NPB;
    int* srcs   = rowptr + 2 * (N_NODES + 1);

    dim3 blk(256);
    int eGrid = (E_EDGES + 255) / 256;
    int mmX = (N_NODES + 63) / 64;                          // 391
    int attnX = (N_NODES * 32 + 255) / 256;                 // 3125

    // ---- CSR ----
    hipMemsetAsync(cnt, 0, 2 * N_NODES * sizeof(int), stream);
    hist2<<<dim3(eGrid, 2), blk, 0, stream>>>(e_writes, e_rev, cnt);
    csr_partial<<<dim3(NPB, 2), blk, 0, stream>>>(cnt, part);
    csr_scanpart<<<1, 128, 0, stream>>>(part);
    csr_write<<<dim3(NPB, 2), blk, 0, stream>>>(cnt, part, rowptr);
    scatter2<<<dim3(eGrid, 2), blk, 0, stream>>>(e_writes, e_rev, cnt, srcs);

    // ---- weight prep ----
    tconv<<<dim3(64, 2), blk, 0, stream>>>(W_in, WTin, HID);
    tconv<<<dim3(64, 4), blk, 0, stream>>>(Wa, WTa, HID);
    tconv<<<dim3(32, 1), blk, 0, stream>>>(W_out, WTout, OUTC);
    prep_qkv<<<4, blk, 0, stream>>>(Wq, bq, Wk, bk, Wv, bv, a_rel, m_rel, WTqkv, bfq);

    // ---- input projection + relu (fp32 A) ----
    mm3_kernel<HID, 0, 1, 1><<<dim3(mmX, 1, 2), blk, 0, stream>>>(
        x_author, x_paper, WTin, WTin + 16384, b_in, b_in + HID,
        nullptr, nullptr, nullptr, cur0, cur1, N_NODES);

    for (int l = 0; l < 2; l++) {
        mm3_kernel<384, 0, 0, 0><<<dim3(mmX, 1, 2), blk, 0, stream>>>(
            cur0, cur1,
            WTqkv + (size_t)(l * 2 + 0) * 49152, WTqkv + (size_t)(l * 2 + 1) * 49152,
            bfq + (l * 2 + 0) * 384, bfq + (l * 2 + 1) * 384,
            nullptr, nullptr, nullptr, qkv0, qkv1, N_NODES);
        attn3_kernel<<<dim3(attnX, 2), blk, 0, stream>>>(
            qkv0, qkv1, rowptr, srcs, p_rel + (size_t)l * 16, agg0, agg1, N_NODES);
        mm3_kernel<HID, 1, 2, 0><<<dim3(mmX, 1, 2), blk, 0, stream>>>(
            agg0, agg1,
            WTa + (size_t)(l * 2 + 0) * 16384, WTa + (size_t)(l * 2 + 1) * 16384,
            ba + (l * 2 + 0) * HID, ba + (l * 2 + 1) * HID,
            cur0, cur1, skip + l * 2, cur0, cur1, N_NODES);
    }

    // ---- final projection (fp32 out) ----
    mm3_kernel<OUTC, 0, 3, 0><<<dim3(mmX, 1, 2), blk, 0, stream>>>(
        cur0, cur1, WTout, WTout, b_out, b_out,
        nullptr, nullptr, nullptr, out, out + (size_t)N_NODES * OUTC, N_NODES);
}

// Round 4
// 522.056 us; speedup vs baseline: 1.2177x; 1.2177x over previous
//
#include <hip/hip_runtime.h>
#include <math.h>

#define N_NODES 25000
#define E_EDGES 250000
#define HID 128
#define OUTC 64
#define NPB 98          // ceil(25000/256)

using bf16x8 = __attribute__((ext_vector_type(8))) short;
using f32x4  = __attribute__((ext_vector_type(4))) float;

__device__ __forceinline__ unsigned short f2bf(float f) {   // RNE float->bf16
    unsigned u = __float_as_uint(f);
    u = (u + 0x7fffu + ((u >> 16) & 1u)) >> 16;
    return (unsigned short)u;
}
__device__ __forceinline__ float bf2f(unsigned short h) {
    return __uint_as_float(((unsigned)h) << 16);
}
__device__ __forceinline__ float gelu_f(float x) {
    return 0.5f * x * (1.0f + erff(x * 0.70710678118654752440f));
}

// ============================ CSR build ============================
__global__ void hist2(const int* __restrict__ e0, const int* __restrict__ e1,
                      int* __restrict__ cnt) {
    int r = blockIdx.y;
    const int* d = (r ? e1 : e0) + E_EDGES;
    int e = blockIdx.x * 256 + threadIdx.x;
    if (e < E_EDGES) atomicAdd(&cnt[r * N_NODES + d[e]], 1);
}

__global__ void csr_partial(const int* __restrict__ cnt, int* __restrict__ part) {
    int r = blockIdx.y, b = blockIdx.x, t = threadIdx.x;
    int idx = b * 256 + t;
    int v = (idx < N_NODES) ? cnt[r * N_NODES + idx] : 0;
    #pragma unroll
    for (int d = 1; d < 64; d <<= 1) v += __shfl_xor(v, d);
    __shared__ int ws[4];
    if ((t & 63) == 0) ws[t >> 6] = v;
    __syncthreads();
    if (t == 0) part[r * NPB + b] = ws[0] + ws[1] + ws[2] + ws[3];
}

__global__ void csr_scanpart(int* __restrict__ part) {
    int w = threadIdx.x >> 6, lane = threadIdx.x & 63;
    int base = w * NPB;
    int a = part[base + lane];
    int b = (lane < NPB - 64) ? part[base + 64 + lane] : 0;
    int va = a, vb = b;
    #pragma unroll
    for (int d = 1; d < 64; d <<= 1) { int u = __shfl_up(va, d); if (lane >= d) va += u; }
    #pragma unroll
    for (int d = 1; d < 64; d <<= 1) { int u = __shfl_up(vb, d); if (lane >= d) vb += u; }
    int tot0 = __shfl(va, 63);
    part[base + lane] = va - a;
    if (lane < NPB - 64) part[base + 64 + lane] = vb - b + tot0;
}

__global__ void csr_write(int* __restrict__ cnt, const int* __restrict__ part,
                          int* __restrict__ rowptr) {
    int r = blockIdx.y, b = blockIdx.x, t = threadIdx.x;
    int idx = b * 256 + t;
    int v = (idx < N_NODES) ? cnt[r * N_NODES + idx] : 0;
    int lane = t & 63, w = t >> 6;
    int iv = v;
    #pragma unroll
    for (int d = 1; d < 64; d <<= 1) { int u = __shfl_up(iv, d); if (lane >= d) iv += u; }
    __shared__ int wtot[4];
    if (lane == 63) wtot[w] = iv;
    __syncthreads();
    int woff = part[r * NPB + b];
    #pragma unroll
    for (int i = 0; i < 4; i++) if (i < w) woff += wtot[i];
    int excl = woff + iv - v;
    if (idx < N_NODES) {
        rowptr[r * (N_NODES + 1) + idx] = excl;
        cnt[r * N_NODES + idx] = excl;
    }
    if (b == 0 && t == 0) rowptr[r * (N_NODES + 1) + N_NODES] = E_EDGES;
}

__global__ void scatter2(const int* __restrict__ e0, const int* __restrict__ e1,
                         int* __restrict__ cursor, int* __restrict__ srcs) {
    int r = blockIdx.y;
    const int* e = r ? e1 : e0;
    int i = blockIdx.x * 256 + threadIdx.x;
    if (i < E_EDGES) {
        int p = atomicAdd(&cursor[r * N_NODES + e[E_EDGES + i]], 1);
        srcs[r * E_EDGES + p] = e[i];
    }
}

// =============== weight prep: transpose fp32 [128][C] -> bf16 [C][128] ===============
__global__ void tconv(const float* __restrict__ src, unsigned short* __restrict__ dst, int C) {
    int m = blockIdx.y;
    int idx = blockIdx.x * 256 + threadIdx.x;
    if (idx >= C * 128) return;
    int c = idx >> 7, k = idx & 127;
    dst[(size_t)m * C * 128 + idx] = f2bf(src[(size_t)m * 128 * C + k * C + c]);
}

// fused QKV' weights, transposed bf16 [p][384col][128k] + fp32 bias [p][384]
// One output element per thread: idx over (c, ik), c = column 0..383, ik = 0..128 (128 = bias).
__global__ __launch_bounds__(256) void prep_qkv(
    const float* __restrict__ Wq, const float* __restrict__ bq,
    const float* __restrict__ Wk, const float* __restrict__ bk,
    const float* __restrict__ Wv, const float* __restrict__ bv,
    const float* __restrict__ a_rel, const float* __restrict__ m_rel,
    unsigned short* __restrict__ WT, float* __restrict__ bfq)
{
    int p = blockIdx.y;                    // l*2+t (relation r == source type t)
    __shared__ float sA[2048], sM[2048];
    for (int i = threadIdx.x; i < 2048; i += 256) {
        sA[i] = a_rel[p * 2048 + i];
        sM[i] = m_rel[p * 2048 + i];
    }
    __syncthreads();
    int idx = blockIdx.x * 256 + threadIdx.x;
    if (idx >= 384 * 129) return;
    int c = idx / 129;
    int ik = idx - c * 129;                // 0..127 weight row, 128 = bias
    const float* wq = Wq + (size_t)p * 16384;
    const float* wk = Wk + (size_t)p * 16384;
    const float* wv = Wv + (size_t)p * 16384;
    float val;
    if (c < 128) {
        val = (ik < 128) ? wq[ik * 128 + c] : bq[p * 128 + c];
    } else if (c < 256) {
        int cc = c - 128, h = cc >> 4, f = cc & 15;
        const float* row = (ik < 128) ? &wk[ik * 128 + h * 16] : &bk[p * 128 + h * 16];
        float s = 0.f;
        #pragma unroll
        for (int d = 0; d < 16; d++) s = fmaf(row[d], sA[h * 256 + d * 16 + f], s);
        val = s;
    } else {
        int cc = c - 256, h = cc >> 4, f = cc & 15;
        const float* row = (ik < 128) ? &wv[ik * 128 + h * 16] : &bv[p * 128 + h * 16];
        float s = 0.f;
        #pragma unroll
        for (int d = 0; d < 16; d++) s = fmaf(row[d], sM[h * 256 + d * 16 + f], s);
        val = s;
    }
    if (ik < 128) WT[(size_t)p * 384 * 128 + (size_t)c * 128 + ik] = f2bf(val);
    else bfq[p * 384 + c] = val;
}

// ============================ MFMA matmul ============================
// C[z] = epilogue(A[z][nrows,128] @ WT[z]^T + b[z]).  WT is bf16 [NOUT][128].
// No LDS: each wave owns 16 rows; A and B fragments loaded directly (16B/lane).
// OUTMODE: 0 bf16 store, 1 relu+bf16, 2 gated residual bf16 (in-place), 3 fp32 store.
template<int NOUT, int GELU_IN, int OUTMODE, int A_FP32>
__global__ __launch_bounds__(256) void mm3_kernel(
    const void* __restrict__ A0, const void* __restrict__ A1,
    const unsigned short* __restrict__ W0, const unsigned short* __restrict__ W1,
    const float* __restrict__ b0, const float* __restrict__ b1,
    const unsigned short* __restrict__ res0, const unsigned short* __restrict__ res1,
    const float* __restrict__ skipp,
    void* __restrict__ C0, void* __restrict__ C1, int nrows)
{
    constexpr int NF = NOUT / 16;
    int z = blockIdx.z;
    const void* Av = z ? A1 : A0;
    const unsigned short* W = z ? W1 : W0;
    const float* bias = z ? b1 : b0;
    const unsigned short* res = z ? res1 : res0;
    void* Cv = z ? C1 : C0;

    int t = threadIdx.x;
    int w = t >> 6, lane = t & 63;
    int lo = lane & 15, hi = lane >> 4;
    int rbase = blockIdx.x * 64 + w * 16;
    int ra = rbase + lo; if (ra > nrows - 1) ra = nrows - 1;

    bf16x8 a[4];
    if (A_FP32) {
        const float* Arow = (const float*)Av + (size_t)ra * HID;
        #pragma unroll
        for (int kk = 0; kk < 4; kk++) {
            const float* p4 = Arow + kk * 32 + hi * 8;
            float4 x0 = *(const float4*)p4;
            float4 x1 = *(const float4*)(p4 + 4);
            bf16x8 v;
            v[0] = (short)f2bf(x0.x); v[1] = (short)f2bf(x0.y);
            v[2] = (short)f2bf(x0.z); v[3] = (short)f2bf(x0.w);
            v[4] = (short)f2bf(x1.x); v[5] = (short)f2bf(x1.y);
            v[6] = (short)f2bf(x1.z); v[7] = (short)f2bf(x1.w);
            a[kk] = v;
        }
    } else {
        const unsigned short* Arow = (const unsigned short*)Av + (size_t)ra * HID;
        #pragma unroll
        for (int kk = 0; kk < 4; kk++) {
            bf16x8 v = *(const bf16x8*)(Arow + kk * 32 + hi * 8);
            if (GELU_IN) {
                #pragma unroll
                for (int j = 0; j < 8; j++)
                    v[j] = (short)f2bf(gelu_f(bf2f((unsigned short)v[j])));
            }
            a[kk] = v;
        }
    }

    f32x4 acc[NF];
    #pragma unroll
    for (int c = 0; c < NF; c++) acc[c] = (f32x4){0.f, 0.f, 0.f, 0.f};

    #pragma unroll
    for (int c = 0; c < NF; c++) {
        const unsigned short* Brow = W + (size_t)(c * 16 + lo) * HID + hi * 8;
        bf16x8 bf0 = *(const bf16x8*)(Brow);
        bf16x8 bf1 = *(const bf16x8*)(Brow + 32);
        bf16x8 bf2 = *(const bf16x8*)(Brow + 64);
        bf16x8 bf3 = *(const bf16x8*)(Brow + 96);
        acc[c] = __builtin_amdgcn_mfma_f32_16x16x32_bf16(a[0], bf0, acc[c], 0, 0, 0);
        acc[c] = __builtin_amdgcn_mfma_f32_16x16x32_bf16(a[1], bf1, acc[c], 0, 0, 0);
        acc[c] = __builtin_amdgcn_mfma_f32_16x16x32_bf16(a[2], bf2, acc[c], 0, 0, 0);
        acc[c] = __builtin_amdgcn_mfma_f32_16x16x32_bf16(a[3], bf3, acc[c], 0, 0, 0);
    }

    float beta = 0.f, omb = 0.f;
    if (OUTMODE == 2) { float sv = skipp[z]; beta = 1.f / (1.f + __expf(-sv)); omb = 1.f - beta; }
    #pragma unroll
    for (int c = 0; c < NF; c++) {
        int col = c * 16 + lo;
        float bb = bias[col];
        #pragma unroll
        for (int j = 0; j < 4; j++) {
            int r = rbase + hi * 4 + j;
            if (r >= nrows) continue;
            float v = acc[c][j] + bb;
            if (OUTMODE == 1) v = fmaxf(v, 0.f);
            if (OUTMODE == 2) v = beta * v + omb * bf2f(res[(size_t)r * HID + col]);
            if (OUTMODE == 3) ((float*)Cv)[(size_t)r * NOUT + col] = v;
            else ((unsigned short*)Cv)[(size_t)r * NOUT + col] = f2bf(v);
        }
    }
}

// ==================== attention: 32 lanes per dst node, bf16 gather ====================
// 1-deep software prefetch: edge i+1's K/V loads issue before edge i's softmax update.
__global__ __launch_bounds__(256) void attn3_kernel(
    const unsigned short* __restrict__ qkv0, const unsigned short* __restrict__ qkv1,
    const int* __restrict__ rowptr, const int* __restrict__ srcs,
    const float* __restrict__ prel,
    unsigned short* __restrict__ agg0, unsigned short* __restrict__ agg1, int n)
{
    int r = blockIdx.y;                    // relation; src type = r, dst type = 1-r
    const unsigned short* qd = r ? qkv0 : qkv1;
    const unsigned short* sv = r ? qkv1 : qkv0;
    unsigned short* agg      = r ? agg0 : agg1;
    const int* rp = rowptr + r * (N_NODES + 1);
    const int* ss = srcs + r * E_EDGES;

    int gid = blockIdx.x * 256 + threadIdx.x;
    int nid = gid >> 5, lane = gid & 31;
    if (nid >= n) return;
    int c0 = lane << 2;
    int h = lane >> 2;
    const unsigned short* qrow = qd + (size_t)nid * 384 + c0;
    float q0 = bf2f(qrow[0]), q1 = bf2f(qrow[1]), q2 = bf2f(qrow[2]), q3 = bf2f(qrow[3]);
    float p = prel[r * 8 + h] * 0.25f;
    float m = -INFINITY, ssum = 0.f;
    float ax = 0.f, ay = 0.f, az = 0.f, aw = 0.f;
    int beg = rp[nid], end = rp[nid + 1];
    if (beg < end) {
        int s0 = ss[beg];
        const unsigned short* srow0 = sv + (size_t)s0 * 384;
        ushort4 kv = *(const ushort4*)(srow0 + 128 + c0);
        ushort4 vv = *(const ushort4*)(srow0 + 256 + c0);
        for (int i = beg; i < end; i++) {
            int inx = i + 1 < end ? i + 1 : end - 1;
            int sn = ss[inx];
            const unsigned short* srn = sv + (size_t)sn * 384;
            ushort4 kvn = *(const ushort4*)(srn + 128 + c0);
            ushort4 vvn = *(const ushort4*)(srn + 256 + c0);
            float part = q0 * bf2f(kv.x) + q1 * bf2f(kv.y) + q2 * bf2f(kv.z) + q3 * bf2f(kv.w);
            part += __shfl_xor(part, 1);
            part += __shfl_xor(part, 2);
            float score = part * p;
            float nm = fmaxf(m, score);
            float resc = __expf(m - nm);
            float e = __expf(score - nm);
            ssum = ssum * resc + e;
            ax = ax * resc + e * bf2f(vv.x);
            ay = ay * resc + e * bf2f(vv.y);
            az = az * resc + e * bf2f(vv.z);
            aw = aw * resc + e * bf2f(vv.w);
            m = nm;
            kv = kvn; vv = vvn;
        }
    }
    float inv = 1.f / (ssum + 1e-16f);
    ushort4 o;
    o.x = f2bf(ax * inv); o.y = f2bf(ay * inv);
    o.z = f2bf(az * inv); o.w = f2bf(aw * inv);
    *(ushort4*)(agg + (size_t)nid * HID + c0) = o;
}

// ============================ orchestration ============================
extern "C" void kernel_launch(void* const* d_in, const int* in_sizes, int n_in,
                              void* d_out, int out_size, void* d_ws, size_t ws_size,
                              hipStream_t stream)
{
    (void)in_sizes; (void)n_in; (void)out_size; (void)ws_size;
    const float* x_author = (const float*)d_in[0];
    const float* x_paper  = (const float*)d_in[1];
    const int*   e_writes = (const int*)d_in[2];
    const int*   e_rev    = (const int*)d_in[3];
    const float* W_in = (const float*)d_in[4];
    const float* b_in = (const float*)d_in[5];
    const float* Wq = (const float*)d_in[6];
    const float* bq = (const float*)d_in[7];
    const float* Wk = (const float*)d_in[8];
    const float* bk = (const float*)d_in[9];
    const float* Wv = (const float*)d_in[10];
    const float* bv = (const float*)d_in[11];
    const float* Wa = (const float*)d_in[12];
    const float* ba = (const float*)d_in[13];
    const float* skip = (const float*)d_in[14];
    const float* a_rel = (const float*)d_in[15];
    const float* m_rel = (const float*)d_in[16];
    const float* p_rel = (const float*)d_in[17];
    const float* W_out = (const float*)d_in[18];
    const float* b_out = (const float*)d_in[19];
    float* out = (float*)d_out;

    const size_t NC = (size_t)N_NODES * HID;       // 3.2M elems
    const size_t NQ = (size_t)N_NODES * 384;
    unsigned short* U = (unsigned short*)d_ws;
    unsigned short* cur0 = U;             unsigned short* cur1 = U + NC;
    unsigned short* agg0 = U + 2 * NC;    unsigned short* agg1 = U + 3 * NC;
    unsigned short* qkv0 = U + 4 * NC;    unsigned short* qkv1 = U + 4 * NC + NQ;
    unsigned short* WTin  = U + 4 * NC + 2 * NQ;            // 2*128*128
    unsigned short* WTqkv = WTin + 2 * 16384;               // 4*384*128
    unsigned short* WTa   = WTqkv + 4 * 49152;              // 4*128*128
    unsigned short* WTout = WTa + 4 * 16384;                // 64*128
    float* bfq = (float*)(WTout + OUTC * 128);              // 4*384 fp32
    int* I      = (int*)(bfq + 4 * 384);
    int* cnt    = I;
    int* part   = I + 2 * N_NODES;
    int* rowptr = part + 2 * NPB;
    int* srcs   = rowptr + 2 * (N_NODES + 1);

    dim3 blk(256);
    int eGrid = (E_EDGES + 255) / 256;
    int mmX = (N_NODES + 63) / 64;                          // 391
    int attnX = (N_NODES * 32 + 255) / 256;                 // 3125
    int prepX = (384 * 129 + 255) / 256;                    // 194

    // ---- CSR ----
    hipMemsetAsync(cnt, 0, 2 * N_NODES * sizeof(int), stream);
    hist2<<<dim3(eGrid, 2), blk, 0, stream>>>(e_writes, e_rev, cnt);
    csr_partial<<<dim3(NPB, 2), blk, 0, stream>>>(cnt, part);
    csr_scanpart<<<1, 128, 0, stream>>>(part);
    csr_write<<<dim3(NPB, 2), blk, 0, stream>>>(cnt, part, rowptr);
    scatter2<<<dim3(eGrid, 2), blk, 0, stream>>>(e_writes, e_rev, cnt, srcs);

    // ---- weight prep ----
    tconv<<<dim3(64, 2), blk, 0, stream>>>(W_in, WTin, HID);
    tconv<<<dim3(64, 4), blk, 0, stream>>>(Wa, WTa, HID);
    tconv<<<dim3(32, 1), blk, 0, stream>>>(W_out, WTout, OUTC);
    prep_qkv<<<dim3(prepX, 4), blk, 0, stream>>>(Wq, bq, Wk, bk, Wv, bv, a_rel, m_rel, WTqkv, bfq);

    // ---- input projection + relu (fp32 A) ----
    mm3_kernel<HID, 0, 1, 1><<<dim3(mmX, 1, 2), blk, 0, stream>>>(
        x_author, x_paper, WTin, WTin + 16384, b_in, b_in + HID,
        nullptr, nullptr, nullptr, cur0, cur1, N_NODES);

    for (int l = 0; l < 2; l++) {
        mm3_kernel<384, 0, 0, 0><<<dim3(mmX, 1, 2), blk, 0, stream>>>(
            cur0, cur1,
            WTqkv + (size_t)(l * 2 + 0) * 49152, WTqkv + (size_t)(l * 2 + 1) * 49152,
            bfq + (l * 2 + 0) * 384, bfq + (l * 2 + 1) * 384,
            nullptr, nullptr, nullptr, qkv0, qkv1, N_NODES);
        attn3_kernel<<<dim3(attnX, 2), blk, 0, stream>>>(
            qkv0, qkv1, rowptr, srcs, p_rel + (size_t)l * 16, agg0, agg1, N_NODES);
        mm3_kernel<HID, 1, 2, 0><<<dim3(mmX, 1, 2), blk, 0, stream>>>(
            agg0, agg1,
            WTa + (size_t)(l * 2 + 0) * 16384, WTa + (size_t)(l * 2 + 1) * 16384,
            ba + (l * 2 + 0) * HID, ba + (l * 2 + 1) * HID,
            cur0, cur1, skip + l * 2, cur0, cur1, N_NODES);
    }

    // ---- final projection (fp32 out) ----
    mm3_kernel<OUTC, 0, 3, 0><<<dim3(mmX, 1, 2), blk, 0, stream>>>(
        cur0, cur1, WTout, WTout, b_out, b_out,
        nullptr, nullptr, nullptr, out, out + (size_t)N_NODES * OUTC, N_NODES);
}

// Round 6
// 392.402 us; speedup vs baseline: 1.6200x; 1.3304x over previous
//
#include <hip/hip_runtime.h>
#include <math.h>

#define N_NODES 25000
#define E_EDGES 250000
#define HID 128
#define OUTC 64
#define NPB 98          // ceil(25000/256)

using bf16x8 = __attribute__((ext_vector_type(8))) short;
using f32x4  = __attribute__((ext_vector_type(4))) float;

__device__ __forceinline__ unsigned short f2bf(float f) {   // RNE float->bf16
    unsigned u = __float_as_uint(f);
    u = (u + 0x7fffu + ((u >> 16) & 1u)) >> 16;
    return (unsigned short)u;
}
__device__ __forceinline__ float bf2f(unsigned short h) {
    return __uint_as_float(((unsigned)h) << 16);
}
__device__ __forceinline__ float gelu_f(float x) {
    return 0.5f * x * (1.0f + erff(x * 0.70710678118654752440f));
}

// ============================ CSR build ============================
__global__ void hist2(const int* __restrict__ e0, const int* __restrict__ e1,
                      int* __restrict__ cnt) {
    int r = blockIdx.y;
    const int* d = (r ? e1 : e0) + E_EDGES;
    int e = blockIdx.x * 256 + threadIdx.x;
    if (e < E_EDGES) atomicAdd(&cnt[r * N_NODES + d[e]], 1);
}

__global__ void csr_partial(const int* __restrict__ cnt, int* __restrict__ part) {
    int r = blockIdx.y, b = blockIdx.x, t = threadIdx.x;
    int idx = b * 256 + t;
    int v = (idx < N_NODES) ? cnt[r * N_NODES + idx] : 0;
    #pragma unroll
    for (int d = 1; d < 64; d <<= 1) v += __shfl_xor(v, d);
    __shared__ int ws[4];
    if ((t & 63) == 0) ws[t >> 6] = v;
    __syncthreads();
    if (t == 0) part[r * NPB + b] = ws[0] + ws[1] + ws[2] + ws[3];
}

__global__ void csr_scanpart(int* __restrict__ part) {
    int w = threadIdx.x >> 6, lane = threadIdx.x & 63;
    int base = w * NPB;
    int a = part[base + lane];
    int b = (lane < NPB - 64) ? part[base + 64 + lane] : 0;
    int va = a, vb = b;
    #pragma unroll
    for (int d = 1; d < 64; d <<= 1) { int u = __shfl_up(va, d); if (lane >= d) va += u; }
    #pragma unroll
    for (int d = 1; d < 64; d <<= 1) { int u = __shfl_up(vb, d); if (lane >= d) vb += u; }
    int tot0 = __shfl(va, 63);
    part[base + lane] = va - a;
    if (lane < NPB - 64) part[base + 64 + lane] = vb - b + tot0;
}

__global__ void csr_write(int* __restrict__ cnt, const int* __restrict__ part,
                          int* __restrict__ rowptr) {
    int r = blockIdx.y, b = blockIdx.x, t = threadIdx.x;
    int idx = b * 256 + t;
    int v = (idx < N_NODES) ? cnt[r * N_NODES + idx] : 0;
    int lane = t & 63, w = t >> 6;
    int iv = v;
    #pragma unroll
    for (int d = 1; d < 64; d <<= 1) { int u = __shfl_up(iv, d); if (lane >= d) iv += u; }
    __shared__ int wtot[4];
    if (lane == 63) wtot[w] = iv;
    __syncthreads();
    int woff = part[r * NPB + b];
    #pragma unroll
    for (int i = 0; i < 4; i++) if (i < w) woff += wtot[i];
    int excl = woff + iv - v;
    if (idx < N_NODES) {
        rowptr[r * (N_NODES + 1) + idx] = excl;
        cnt[r * N_NODES + idx] = excl;
    }
    if (b == 0 && t == 0) rowptr[r * (N_NODES + 1) + N_NODES] = E_EDGES;
}

__global__ void scatter2(const int* __restrict__ e0, const int* __restrict__ e1,
                         int* __restrict__ cursor, int* __restrict__ srcs) {
    int r = blockIdx.y;
    const int* e = r ? e1 : e0;
    int i = blockIdx.x * 256 + threadIdx.x;
    if (i < E_EDGES) {
        int p = atomicAdd(&cursor[r * N_NODES + e[E_EDGES + i]], 1);
        srcs[r * E_EDGES + p] = e[i];
    }
}

// =============== weight prep: transpose fp32 [128][C] -> bf16 [C][128] ===============
__global__ void tconv(const float* __restrict__ src, unsigned short* __restrict__ dst, int C) {
    int m = blockIdx.y;
    int idx = blockIdx.x * 256 + threadIdx.x;
    if (idx >= C * 128) return;
    int c = idx >> 7, k = idx & 127;
    dst[(size_t)m * C * 128 + idx] = f2bf(src[(size_t)m * 128 * C + k * C + c]);
}

// fused QKV' weights, transposed bf16 [p][384col][128k] + fp32 bias [p][384]
__global__ __launch_bounds__(256) void prep_qkv(
    const float* __restrict__ Wq, const float* __restrict__ bq,
    const float* __restrict__ Wk, const float* __restrict__ bk,
    const float* __restrict__ Wv, const float* __restrict__ bv,
    const float* __restrict__ a_rel, const float* __restrict__ m_rel,
    unsigned short* __restrict__ WT, float* __restrict__ bfq)
{
    int p = blockIdx.y;                    // l*2+t (relation r == source type t)
    __shared__ float sA[2048], sM[2048];
    for (int i = threadIdx.x; i < 2048; i += 256) {
        sA[i] = a_rel[p * 2048 + i];
        sM[i] = m_rel[p * 2048 + i];
    }
    __syncthreads();
    int idx = blockIdx.x * 256 + threadIdx.x;
    if (idx >= 384 * 129) return;
    int c = idx / 129;
    int ik = idx - c * 129;                // 0..127 weight row, 128 = bias
    const float* wq = Wq + (size_t)p * 16384;
    const float* wk = Wk + (size_t)p * 16384;
    const float* wv = Wv + (size_t)p * 16384;
    float val;
    if (c < 128) {
        val = (ik < 128) ? wq[ik * 128 + c] : bq[p * 128 + c];
    } else if (c < 256) {
        int cc = c - 128, h = cc >> 4, f = cc & 15;
        const float* row = (ik < 128) ? &wk[ik * 128 + h * 16] : &bk[p * 128 + h * 16];
        float s = 0.f;
        #pragma unroll
        for (int d = 0; d < 16; d++) s = fmaf(row[d], sA[h * 256 + d * 16 + f], s);
        val = s;
    } else {
        int cc = c - 256, h = cc >> 4, f = cc & 15;
        const float* row = (ik < 128) ? &wv[ik * 128 + h * 16] : &bv[p * 128 + h * 16];
        float s = 0.f;
        #pragma unroll
        for (int d = 0; d < 16; d++) s = fmaf(row[d], sM[h * 256 + d * 16 + f], s);
        val = s;
    }
    if (ik < 128) WT[(size_t)p * 384 * 128 + (size_t)c * 128 + ik] = f2bf(val);
    else bfq[p * 384 + c] = val;
}

// ============================ MFMA matmul (LDS-staged W) ============================
// C[z] = epilogue(A[z][nrows,128] @ WT[z]^T + b[z]);  WT bf16 [NOUT][128].
// Block: 256 thr = 4 waves, BM=128 rows x BN cols; W-tile (BN x 128) staged once in
// LDS with XOR chunk-swizzle (ch ^= col&7) -> conflict-free ds_read_b128 fragments.
// OUTMODE: 0 bf16 store, 1 relu+bf16, 2 gated residual bf16 (in-place), 3 fp32 store.
template<int NOUT, int BN, int OUTMODE, int A_FP32>
__global__ __launch_bounds__(256) void mm4_kernel(
    const void* __restrict__ A0, const void* __restrict__ A1,
    const unsigned short* __restrict__ W0, const unsigned short* __restrict__ W1,
    const float* __restrict__ b0, const float* __restrict__ b1,
    const unsigned short* __restrict__ res0, const unsigned short* __restrict__ res1,
    const float* __restrict__ skipp,
    void* __restrict__ C0, void* __restrict__ C1, int nrows)
{
    constexpr int CF = BN / 16;
    __shared__ unsigned short sW[BN * 128];
    int z = blockIdx.z;
    const void* Av = z ? A1 : A0;
    const unsigned short* W = z ? W1 : W0;
    const float* bias = z ? b1 : b0;
    const unsigned short* res = z ? res1 : res0;
    void* Cv = z ? C1 : C0;

    int t = threadIdx.x;
    int w = t >> 6, lane = t & 63, lo = lane & 15, hi = lane >> 4;
    int col0 = blockIdx.y * BN;
    int rowbase = blockIdx.x * 128 + w * 32;

    // ---- stage swizzled W tile: sW[col*128 + (ch^(col&7))*8] = Wg[col*128 + ch*8]
    const unsigned short* Wg = W + (size_t)col0 * 128;
    #pragma unroll
    for (int it = 0; it < BN / 16; ++it) {            // BN*16 chunks / 256 threads
        int idx = it * 256 + t;
        int col = idx >> 4, ch = idx & 15;
        bf16x8 v = *(const bf16x8*)(Wg + (size_t)col * 128 + ch * 8);
        *(bf16x8*)&sW[col * 128 + ((ch ^ (col & 7)) << 3)] = v;
    }

    // ---- A fragments (2 row-frags x 4 k-frags), loads overlap the staging
    bf16x8 a[2][4];
    #pragma unroll
    for (int rf = 0; rf < 2; rf++) {
        int r = rowbase + rf * 16 + lo;
        if (r > nrows - 1) r = nrows - 1;
        if (A_FP32) {
            const float* Arow = (const float*)Av + (size_t)r * HID;
            #pragma unroll
            for (int kk = 0; kk < 4; kk++) {
                float4 x0 = *(const float4*)(Arow + kk * 32 + hi * 8);
                float4 x1 = *(const float4*)(Arow + kk * 32 + hi * 8 + 4);
                bf16x8 v;
                v[0] = (short)f2bf(x0.x); v[1] = (short)f2bf(x0.y);
                v[2] = (short)f2bf(x0.z); v[3] = (short)f2bf(x0.w);
                v[4] = (short)f2bf(x1.x); v[5] = (short)f2bf(x1.y);
                v[6] = (short)f2bf(x1.z); v[7] = (short)f2bf(x1.w);
                a[rf][kk] = v;
            }
        } else {
            const unsigned short* Arow = (const unsigned short*)Av + (size_t)r * HID;
            #pragma unroll
            for (int kk = 0; kk < 4; kk++)
                a[rf][kk] = *(const bf16x8*)(Arow + kk * 32 + hi * 8);
        }
    }
    __syncthreads();

    f32x4 acc[2][CF];
    #pragma unroll
    for (int rf = 0; rf < 2; rf++)
        #pragma unroll
        for (int cf = 0; cf < CF; cf++) acc[rf][cf] = (f32x4){0.f, 0.f, 0.f, 0.f};

    #pragma unroll
    for (int cf = 0; cf < CF; cf++) {
        int colb = cf * 16 + lo;
        int sbase = colb * 128;
        int sx = colb & 7;
        bf16x8 bfr[4];
        #pragma unroll
        for (int kk = 0; kk < 4; kk++) {
            int ch = kk * 4 + hi;
            bfr[kk] = *(const bf16x8*)&sW[sbase + ((ch ^ sx) << 3)];
        }
        #pragma unroll
        for (int kk = 0; kk < 4; kk++) {
            acc[0][cf] = __builtin_amdgcn_mfma_f32_16x16x32_bf16(a[0][kk], bfr[kk], acc[0][cf], 0, 0, 0);
            acc[1][cf] = __builtin_amdgcn_mfma_f32_16x16x32_bf16(a[1][kk], bfr[kk], acc[1][cf], 0, 0, 0);
        }
    }

    float beta = 0.f, omb = 0.f;
    if (OUTMODE == 2) { float sv = skipp[z]; beta = 1.f / (1.f + __expf(-sv)); omb = 1.f - beta; }
    #pragma unroll
    for (int rf = 0; rf < 2; rf++) {
        #pragma unroll
        for (int cf = 0; cf < CF; cf++) {
            int col = col0 + cf * 16 + lo;
            float bb = bias[col];
            #pragma unroll
            for (int j = 0; j < 4; j++) {
                int r = rowbase + rf * 16 + hi * 4 + j;
                if (r >= nrows) continue;
                float v = acc[rf][cf][j] + bb;
                if (OUTMODE == 1) v = fmaxf(v, 0.f);
                if (OUTMODE == 2) v = beta * v + omb * bf2f(res[(size_t)r * NOUT + col]);
                if (OUTMODE == 3) ((float*)Cv)[(size_t)r * NOUT + col] = v;
                else ((unsigned short*)Cv)[(size_t)r * NOUT + col] = f2bf(v);
            }
        }
    }
}

// ==================== attention: 32 lanes per dst node, bf16 gather ====================
// 1-deep prefetch; epilogue applies gelu (so out-proj matmul skips the erff tax).
__global__ __launch_bounds__(256) void attn3_kernel(
    const unsigned short* __restrict__ qkv0, const unsigned short* __restrict__ qkv1,
    const int* __restrict__ rowptr, const int* __restrict__ srcs,
    const float* __restrict__ prel,
    unsigned short* __restrict__ agg0, unsigned short* __restrict__ agg1, int n)
{
    int r = blockIdx.y;                    // relation; src type = r, dst type = 1-r
    const unsigned short* qd = r ? qkv0 : qkv1;
    const unsigned short* sv = r ? qkv1 : qkv0;
    unsigned short* agg      = r ? agg0 : agg1;
    const int* rp = rowptr + r * (N_NODES + 1);
    const int* ss = srcs + r * E_EDGES;

    int gid = blockIdx.x * 256 + threadIdx.x;
    int nid = gid >> 5, lane = gid & 31;
    if (nid >= n) return;
    int c0 = lane << 2;
    int h = lane >> 2;
    const unsigned short* qrow = qd + (size_t)nid * 384 + c0;
    float q0 = bf2f(qrow[0]), q1 = bf2f(qrow[1]), q2 = bf2f(qrow[2]), q3 = bf2f(qrow[3]);
    float p = prel[r * 8 + h] * 0.25f;
    float m = -INFINITY, ssum = 0.f;
    float ax = 0.f, ay = 0.f, az = 0.f, aw = 0.f;
    int beg = rp[nid], end = rp[nid + 1];
    if (beg < end) {
        int s0 = ss[beg];
        const unsigned short* srow0 = sv + (size_t)s0 * 384;
        ushort4 kv = *(const ushort4*)(srow0 + 128 + c0);
        ushort4 vv = *(const ushort4*)(srow0 + 256 + c0);
        for (int i = beg; i < end; i++) {
            int inx = i + 1 < end ? i + 1 : end - 1;
            int sn = ss[inx];
            const unsigned short* srn = sv + (size_t)sn * 384;
            ushort4 kvn = *(const ushort4*)(srn + 128 + c0);
            ushort4 vvn = *(const ushort4*)(srn + 256 + c0);
            float part = q0 * bf2f(kv.x) + q1 * bf2f(kv.y) + q2 * bf2f(kv.z) + q3 * bf2f(kv.w);
            part += __shfl_xor(part, 1);
            part += __shfl_xor(part, 2);
            float score = part * p;
            float nm = fmaxf(m, score);
            float resc = __expf(m - nm);
            float e = __expf(score - nm);
            ssum = ssum * resc + e;
            ax = ax * resc + e * bf2f(vv.x);
            ay = ay * resc + e * bf2f(vv.y);
            az = az * resc + e * bf2f(vv.z);
            aw = aw * resc + e * bf2f(vv.w);
            m = nm;
            kv = kvn; vv = vvn;
        }
    }
    float inv = 1.f / (ssum + 1e-16f);
    ushort4 o;
    o.x = f2bf(gelu_f(ax * inv)); o.y = f2bf(gelu_f(ay * inv));
    o.z = f2bf(gelu_f(az * inv)); o.w = f2bf(gelu_f(aw * inv));
    *(ushort4*)(agg + (size_t)nid * HID + c0) = o;
}

// ============================ orchestration ============================
extern "C" void kernel_launch(void* const* d_in, const int* in_sizes, int n_in,
                              void* d_out, int out_size, void* d_ws, size_t ws_size,
                              hipStream_t stream)
{
    (void)in_sizes; (void)n_in; (void)out_size; (void)ws_size;
    const float* x_author = (const float*)d_in[0];
    const float* x_paper  = (const float*)d_in[1];
    const int*   e_writes = (const int*)d_in[2];
    const int*   e_rev    = (const int*)d_in[3];
    const float* W_in = (const float*)d_in[4];
    const float* b_in = (const float*)d_in[5];
    const float* Wq = (const float*)d_in[6];
    const float* bq = (const float*)d_in[7];
    const float* Wk = (const float*)d_in[8];
    const float* bk = (const float*)d_in[9];
    const float* Wv = (const float*)d_in[10];
    const float* bv = (const float*)d_in[11];
    const float* Wa = (const float*)d_in[12];
    const float* ba = (const float*)d_in[13];
    const float* skip = (const float*)d_in[14];
    const float* a_rel = (const float*)d_in[15];
    const float* m_rel = (const float*)d_in[16];
    const float* p_rel = (const float*)d_in[17];
    const float* W_out = (const float*)d_in[18];
    const float* b_out = (const float*)d_in[19];
    float* out = (float*)d_out;

    const size_t NC = (size_t)N_NODES * HID;       // 3.2M elems
    const size_t NQ = (size_t)N_NODES * 384;
    unsigned short* U = (unsigned short*)d_ws;
    unsigned short* cur0 = U;             unsigned short* cur1 = U + NC;
    unsigned short* agg0 = U + 2 * NC;    unsigned short* agg1 = U + 3 * NC;
    unsigned short* qkv0 = U + 4 * NC;    unsigned short* qkv1 = U + 4 * NC + NQ;
    unsigned short* WTin  = U + 4 * NC + 2 * NQ;            // 2*128*128
    unsigned short* WTqkv = WTin + 2 * 16384;               // 4*384*128
    unsigned short* WTa   = WTqkv + 4 * 49152;              // 4*128*128
    unsigned short* WTout = WTa + 4 * 16384;                // 64*128
    float* bfq = (float*)(WTout + OUTC * 128);              // 4*384 fp32
    int* I      = (int*)(bfq + 4 * 384);
    int* cnt    = I;
    int* part   = I + 2 * N_NODES;
    int* rowptr = part + 2 * NPB;
    int* srcs   = rowptr + 2 * (N_NODES + 1);

    dim3 blk(256);
    int eGrid = (E_EDGES + 255) / 256;
    int mmX = (N_NODES + 127) / 128;                        // 196
    int attnX = (N_NODES * 32 + 255) / 256;                 // 3125
    int prepX = (384 * 129 + 255) / 256;                    // 194

    // ---- CSR ----
    hipMemsetAsync(cnt, 0, 2 * N_NODES * sizeof(int), stream);
    hist2<<<dim3(eGrid, 2), blk, 0, stream>>>(e_writes, e_rev, cnt);
    csr_partial<<<dim3(NPB, 2), blk, 0, stream>>>(cnt, part);
    csr_scanpart<<<1, 128, 0, stream>>>(part);
    csr_write<<<dim3(NPB, 2), blk, 0, stream>>>(cnt, part, rowptr);
    scatter2<<<dim3(eGrid, 2), blk, 0, stream>>>(e_writes, e_rev, cnt, srcs);

    // ---- weight prep ----
    tconv<<<dim3(64, 2), blk, 0, stream>>>(W_in, WTin, HID);
    tconv<<<dim3(64, 4), blk, 0, stream>>>(Wa, WTa, HID);
    tconv<<<dim3(32, 1), blk, 0, stream>>>(W_out, WTout, OUTC);
    prep_qkv<<<dim3(prepX, 4), blk, 0, stream>>>(Wq, bq, Wk, bk, Wv, bv, a_rel, m_rel, WTqkv, bfq);

    // ---- input projection + relu (fp32 A) ----
    mm4_kernel<HID, 128, 1, 1><<<dim3(mmX, 1, 2), blk, 0, stream>>>(
        x_author, x_paper, WTin, WTin + 16384, b_in, b_in + HID,
        nullptr, nullptr, nullptr, cur0, cur1, N_NODES);

    for (int l = 0; l < 2; l++) {
        mm4_kernel<384, 128, 0, 0><<<dim3(mmX, 3, 2), blk, 0, stream>>>(
            cur0, cur1,
            WTqkv + (size_t)(l * 2 + 0) * 49152, WTqkv + (size_t)(l * 2 + 1) * 49152,
            bfq + (l * 2 + 0) * 384, bfq + (l * 2 + 1) * 384,
            nullptr, nullptr, nullptr, qkv0, qkv1, N_NODES);
        attn3_kernel<<<dim3(attnX, 2), blk, 0, stream>>>(
            qkv0, qkv1, rowptr, srcs, p_rel + (size_t)l * 16, agg0, agg1, N_NODES);
        mm4_kernel<HID, 128, 2, 0><<<dim3(mmX, 1, 2), blk, 0, stream>>>(
            agg0, agg1,
            WTa + (size_t)(l * 2 + 0) * 16384, WTa + (size_t)(l * 2 + 1) * 16384,
            ba + (l * 2 + 0) * HID, ba + (l * 2 + 1) * HID,
            cur0, cur1, skip + l * 2, cur0, cur1, N_NODES);
    }

    // ---- final projection (fp32 out) ----
    mm4_kernel<OUTC, 64, 3, 0><<<dim3(mmX, 1, 2), blk, 0, stream>>>(
        cur0, cur1, WTout, WTout, b_out, b_out,
        nullptr, nullptr, nullptr, out, out + (size_t)N_NODES * OUTC, N_NODES);
}